// Round 2
// baseline (838.765 us; speedup 1.0000x reference)
//
#include <hip/hip_runtime.h>
#include <cstdint>
#include <cstddef>

#define B_   4096   // batch
#define ISZ  1024   // input size
#define SW   4096   // state width (input state last dim)
#define OHW  2048   // output hidden width (4 depths x 512)
#define HU_  512    // hidden units per (depth,stack)
#define NG   2048   // 4*HU gate rows per (depth,stack)

typedef float f32x4 __attribute__((ext_vector_type(4)));
typedef short bf16x8 __attribute__((ext_vector_type(8)));

__device__ __forceinline__ short f2bf(float x) {
    union { float f; unsigned u; } v; v.f = x;
    unsigned r = v.u + 0x7fffu + ((v.u >> 16) & 1u);   // RNE
    return (short)(r >> 16);
}
__device__ __forceinline__ float sigm(float x)   { return 1.f / (1.f + __expf(-x)); }
__device__ __forceinline__ float tanh_f(float x) { return 2.f / (1.f + __expf(-2.f * x)) - 1.f; }

// async global->LDS, 16B per lane; LDS dest is wave-uniform base + lane*16.
__device__ __forceinline__ void async16(const void* g, void* l) {
    __builtin_amdgcn_global_load_lds((__attribute__((address_space(1))) void*)g,
                                     (__attribute__((address_space(3))) void*)l,
                                     16, 0, 0);
}

// ---------------------------------------------------------------- flat f32 -> bf16
__global__ __launch_bounds__(256) void cvt_kernel(const float* __restrict__ src,
                                                  short* __restrict__ dst, long n) {
    long i = ((long)blockIdx.x * 256 + threadIdx.x) * 8;
    if (i >= n) return;
    float4 a = *(const float4*)(src + i);
    float4 b = *(const float4*)(src + i + 4);
    bf16x8 o;
    o[0] = f2bf(a.x); o[1] = f2bf(a.y); o[2] = f2bf(a.z); o[3] = f2bf(a.w);
    o[4] = f2bf(b.x); o[5] = f2bf(b.y); o[6] = f2bf(b.z); o[7] = f2bf(b.w);
    *(bf16x8*)(dst + i) = o;
}

// ---- strided: take first OHW cols of each SW-wide row (state[0,:,:,0:2048]) -> bf16
__global__ __launch_bounds__(256) void cvt_h_kernel(const float* __restrict__ src,
                                                    short* __restrict__ dst) {
    long i = ((long)blockIdx.x * 256 + threadIdx.x) * 8;   // over 2*B*OHW
    long row = i >> 11;              // /2048
    long c   = i & 2047;
    const float* s = src + row * SW + c;
    float4 a = *(const float4*)(s);
    float4 b = *(const float4*)(s + 4);
    bf16x8 o;
    o[0] = f2bf(a.x); o[1] = f2bf(a.y); o[2] = f2bf(a.z); o[3] = f2bf(a.w);
    o[4] = f2bf(b.x); o[5] = f2bf(b.y); o[6] = f2bf(b.z); o[7] = f2bf(b.w);
    *(bf16x8*)(dst + i) = o;
}

// ---------------------------------------------------------------- fused gates GEMM + LSTM cell
// Block: 256 thr (4 waves). Tile: 128 batch-rows x 128 gate-cols (= 4 gates x 32 hidden).
// K phases: K1=1024 (dec_input @ W_ih^T), K2=512 (hx @ W_hh^T), accumulated together.
// LDS tiles 128x64 bf16, XOR-swizzled 8-elem col-blocks: (r, c8) stored at (r, c8^(r&7)).
__global__ __launch_bounds__(256) void gates_kernel(
    const short* __restrict__ A1, long a1_dstride,       // bf16 dec_input (row stride ISZ)
    const short* __restrict__ Hb,                        // bf16 h-state (2,B,OHW)
    const short* __restrict__ Wihb, const short* __restrict__ Whhb,
    const float* __restrict__ b_ih, const float* __restrict__ b_hh,
    const float* __restrict__ state,                     // f32 original (2,2,B,SW)
    float* __restrict__ out_ho, float* __restrict__ out_state,
    short* __restrict__ h0b,                             // bf16 h_out (stack0 only)
    int j)
{
    __shared__ __align__(16) short sA[128 * 64];
    __shared__ __align__(16) short sB[128 * 64];

    const int t    = threadIdx.x;
    const int wave = t >> 6, lane = t & 63;
    const int ln16 = lane & 15, q = lane >> 4;
    const int d  = blockIdx.z;
    const int M0 = blockIdx.x * 128;
    const int h0 = blockIdx.y * 32;
    const int s  = d * HU_;

    const short* A1d = A1 + (size_t)d * a1_dstride;
    const short* A2  = Hb + (size_t)j * B_ * OHW + s;                 // row stride OHW
    const short* W1  = Wihb + (size_t)(d * 2 + j) * NG * ISZ;
    const short* W2  = Whhb + (size_t)(d * 2 + j) * NG * HU_;
    const float* bi_ = b_ih + (size_t)(d * 2 + j) * NG;
    const float* bh_ = b_hh + (size_t)(d * 2 + j) * NG;

    const int srow = wave * 8 + (lane >> 3);                    // row within a 32-row issue
    const int scol = (((lane & 7) ^ (lane >> 3)) << 3);         // swizzled source col (elems)

    f32x4 acc[2][8];
#pragma unroll
    for (int mt = 0; mt < 2; mt++)
#pragma unroll
        for (int nt = 0; nt < 8; nt++) acc[mt][nt] = (f32x4){0.f, 0.f, 0.f, 0.f};

    auto compute_tile = [&]() {
#pragma unroll
        for (int ks = 0; ks < 2; ks++) {
            const int kb = ks * 4 + q;            // col-block 0..7
            bf16x8 a[2], b[8];
#pragma unroll
            for (int mt = 0; mt < 2; mt++) {
                const int m = wave * 32 + mt * 16 + ln16;
                a[mt] = *(const bf16x8*)&sA[m * 64 + ((kb ^ (m & 7)) << 3)];
            }
#pragma unroll
            for (int nt = 0; nt < 8; nt++) {
                const int n = nt * 16 + ln16;
                b[nt] = *(const bf16x8*)&sB[n * 64 + ((kb ^ (n & 7)) << 3)];
            }
#pragma unroll
            for (int mt = 0; mt < 2; mt++)
#pragma unroll
                for (int nt = 0; nt < 8; nt++)
                    acc[mt][nt] = __builtin_amdgcn_mfma_f32_16x16x32_bf16(a[mt], b[nt], acc[mt][nt], 0, 0, 0);
        }
    };

    // phase 1: dec_input @ W_ih^T, K = 1024
    for (int k0 = 0; k0 < ISZ; k0 += 64) {
#pragma unroll
        for (int it = 0; it < 4; it++)
            async16(A1d + (size_t)(M0 + it * 32 + srow) * ISZ + k0 + scol,
                    &sA[(it * 32 + wave * 8) * 64]);
#pragma unroll
        for (int it = 0; it < 4; it++)     // issue it == gate it (32 rows each)
            async16(W1 + (size_t)(it * HU_ + h0 + srow) * ISZ + k0 + scol,
                    &sB[(it * 32 + wave * 8) * 64]);
        __syncthreads();
        compute_tile();
        __syncthreads();
    }
    // phase 2: hx @ W_hh^T, K = 512
    for (int k0 = 0; k0 < HU_; k0 += 64) {
#pragma unroll
        for (int it = 0; it < 4; it++)
            async16(A2 + (size_t)(M0 + it * 32 + srow) * OHW + k0 + scol,
                    &sA[(it * 32 + wave * 8) * 64]);
#pragma unroll
        for (int it = 0; it < 4; it++)
            async16(W2 + (size_t)(it * HU_ + h0 + srow) * HU_ + k0 + scol,
                    &sB[(it * 32 + wave * 8) * 64]);
        __syncthreads();
        compute_tile();
        __syncthreads();
    }

    // epilogue: fused LSTM cell. D layout: col = lane&15, row = q*4 + reg.
#pragma unroll
    for (int mt = 0; mt < 2; mt++) {
#pragma unroll
        for (int nh = 0; nh < 2; nh++) {
            const int h   = h0 + nh * 16 + ln16;       // 0..511
            const int col = s + h;                     // 0..2047
            const float b_i = bi_[h]          + bh_[h];
            const float b_f = bi_[512 + h]    + bh_[512 + h];
            const float b_g = bi_[1024 + h]   + bh_[1024 + h];
            const float b_o = bi_[1536 + h]   + bh_[1536 + h];
            const f32x4 ai = acc[mt][0 + nh];
            const f32x4 af = acc[mt][2 + nh];
            const f32x4 ag = acc[mt][4 + nh];
            const f32x4 ao = acc[mt][6 + nh];
#pragma unroll
            for (int r = 0; r < 4; r++) {
                const int m = M0 + wave * 32 + mt * 16 + q * 4 + r;
                const float hx = state[((size_t)(j)     * B_ + m) * SW + col];  // state[0,j]
                const float cx = state[((size_t)(2 + j) * B_ + m) * SW + col];  // state[1,j]
                const float gi = sigm(ai[r] + b_i);
                const float gf = sigm(af[r] + b_f);
                const float gg = tanh_f(ag[r] + b_g);
                const float go = sigm(ao[r] + b_o);
                const float c_out = gf * cx + gi * gg;
                const float h_out = go * tanh_f(c_out);
                out_state[((size_t)(j)     * B_ + m) * OHW + col] = h_out + hx;  // newH[j]
                out_state[((size_t)(2 + j) * B_ + m) * OHW + col] = c_out;       // newC[j]
                if (j == 1) out_ho[(size_t)m * OHW + col] = h_out + hx;
                else        h0b[((size_t)d * B_ + m) * HU_ + h] = f2bf(h_out);   // pre-residual
            }
        }
    }
}

// ---------------------------------------------------------------- proj: dec1 = input + h0 @ proj_W^T + proj_b (bf16 out)
__global__ __launch_bounds__(256) void proj_kernel(
    const short* __restrict__ h0b, const short* __restrict__ PWb,
    const float* __restrict__ input, const float* __restrict__ proj_b,
    short* __restrict__ dec1b)
{
    __shared__ __align__(16) short sA[128 * 64];
    __shared__ __align__(16) short sB[128 * 64];

    const int t    = threadIdx.x;
    const int wave = t >> 6, lane = t & 63;
    const int ln16 = lane & 15, q = lane >> 4;
    const int d  = blockIdx.z;
    const int M0 = blockIdx.x * 128;
    const int N0 = blockIdx.y * 128;

    const short* A = h0b + (size_t)d * B_ * HU_;

    const int srow = wave * 8 + (lane >> 3);
    const int scol = (((lane & 7) ^ (lane >> 3)) << 3);

    f32x4 acc[2][8];
#pragma unroll
    for (int mt = 0; mt < 2; mt++)
#pragma unroll
        for (int nt = 0; nt < 8; nt++) acc[mt][nt] = (f32x4){0.f, 0.f, 0.f, 0.f};

    for (int k0 = 0; k0 < HU_; k0 += 64) {
#pragma unroll
        for (int it = 0; it < 4; it++)
            async16(A + (size_t)(M0 + it * 32 + srow) * HU_ + k0 + scol,
                    &sA[(it * 32 + wave * 8) * 64]);
#pragma unroll
        for (int it = 0; it < 4; it++)
            async16(PWb + (size_t)(N0 + it * 32 + srow) * HU_ + k0 + scol,
                    &sB[(it * 32 + wave * 8) * 64]);
        __syncthreads();
#pragma unroll
        for (int ks = 0; ks < 2; ks++) {
            const int kb = ks * 4 + q;
            bf16x8 a[2], b[8];
#pragma unroll
            for (int mt = 0; mt < 2; mt++) {
                const int m = wave * 32 + mt * 16 + ln16;
                a[mt] = *(const bf16x8*)&sA[m * 64 + ((kb ^ (m & 7)) << 3)];
            }
#pragma unroll
            for (int nt = 0; nt < 8; nt++) {
                const int n = nt * 16 + ln16;
                b[nt] = *(const bf16x8*)&sB[n * 64 + ((kb ^ (n & 7)) << 3)];
            }
#pragma unroll
            for (int mt = 0; mt < 2; mt++)
#pragma unroll
                for (int nt = 0; nt < 8; nt++)
                    acc[mt][nt] = __builtin_amdgcn_mfma_f32_16x16x32_bf16(a[mt], b[nt], acc[mt][nt], 0, 0, 0);
        }
        __syncthreads();
    }

#pragma unroll
    for (int mt = 0; mt < 2; mt++) {
#pragma unroll
        for (int nt = 0; nt < 8; nt++) {
            const int n = N0 + nt * 16 + ln16;
            const float pb = proj_b[n];
#pragma unroll
            for (int r = 0; r < 4; r++) {
                const int m = M0 + wave * 32 + mt * 16 + q * 4 + r;
                const float y = acc[mt][nt][r] + input[(size_t)m * ISZ + n] + pb;
                dec1b[((size_t)d * B_ + m) * ISZ + n] = f2bf(y);
            }
        }
    }
}

// ---------------------------------------------------------------- launch
extern "C" void kernel_launch(void* const* d_in, const int* in_sizes, int n_in,
                              void* d_out, int out_size, void* d_ws, size_t ws_size,
                              hipStream_t stream)
{
    const float* input  = (const float*)d_in[0];
    const float* state  = (const float*)d_in[1];
    const float* W_ih   = (const float*)d_in[2];
    const float* W_hh   = (const float*)d_in[3];
    const float* b_ih   = (const float*)d_in[4];
    const float* b_hh   = (const float*)d_in[5];
    const float* proj_W = (const float*)d_in[6];
    const float* proj_b = (const float*)d_in[7];

    float* out_ho    = (float*)d_out;                    // (B, OHW)
    float* out_state = out_ho + (size_t)B_ * OHW;        // (2, 2, B, OHW)

    short* ws    = (short*)d_ws;
    short* Wihb  = ws;                                   // 8 x NG x ISZ   (32 MB)
    short* Whhb  = Wihb + (size_t)8 * NG * ISZ;          // 8 x NG x HU    (16 MB)
    short* PWb   = Whhb + (size_t)8 * NG * HU_;          // ISZ x HU       ( 1 MB)
    short* Hb    = PWb  + (size_t)ISZ * HU_;             // 2 x B x OHW    (32 MB)
    short* h0b   = Hb   + (size_t)2 * B_ * OHW;          // 4 x B x HU     (16 MB)
    short* dec1b = h0b  + (size_t)4 * B_ * HU_;          // 4 x B x ISZ    (32 MB)
    short* Xb    = dec1b;                                // B x ISZ — aliases dec1b head
                                                         // (Xb dead before proj writes dec1b)

    {
        long n;
        n = (long)8 * NG * ISZ;  cvt_kernel<<<dim3((unsigned)(n / 8 / 256)), 256, 0, stream>>>(W_ih,   Wihb, n);
        n = (long)8 * NG * HU_;  cvt_kernel<<<dim3((unsigned)(n / 8 / 256)), 256, 0, stream>>>(W_hh,   Whhb, n);
        n = (long)ISZ * HU_;     cvt_kernel<<<dim3((unsigned)(n / 8 / 256)), 256, 0, stream>>>(proj_W, PWb,  n);
        n = (long)B_ * ISZ;      cvt_kernel<<<dim3((unsigned)(n / 8 / 256)), 256, 0, stream>>>(input,  Xb,   n);
        n = (long)2 * B_ * OHW;  cvt_h_kernel<<<dim3((unsigned)(n / 8 / 256)), 256, 0, stream>>>(state, Hb);
    }

    // stack 0 (all 4 depths): gates + cell, writes newH[0]/newC[0] and h0b
    gates_kernel<<<dim3(32, 16, 4), 256, 0, stream>>>(Xb, 0L, Hb, Wihb, Whhb,
                                                      b_ih, b_hh, state,
                                                      out_ho, out_state, h0b, 0);
    // dec1 = input + h_out0 @ proj_W^T + proj_b (per depth), bf16
    proj_kernel<<<dim3(32, 8, 4), 256, 0, stream>>>(h0b, PWb, input, proj_b, dec1b);
    // stack 1 (all 4 depths): gates + cell, writes newH[1]/newC[1] and ho
    gates_kernel<<<dim3(32, 16, 4), 256, 0, stream>>>(dec1b, (long)B_ * ISZ, Hb, Wihb, Whhb,
                                                      b_ih, b_hh, state,
                                                      out_ho, out_state, nullptr, 1);
}